// Round 6
// baseline (238.609 us; speedup 1.0000x reference)
//
#include <hip/hip_runtime.h>
#include <hip/hip_fp16.h>
#include <math.h>

// Instant-NGP forward:
//   sort:   bucket points by quantized (z,y,x) key (32768 bins) so each wave
//           covers a small spatial box -> hash-gather cache lines are shared
//           across lanes at coarse/mid levels (TA coalesces same-line lanes).
//   conv:   table f32 -> fp16-pair table (4B/entry) in ws.
//   encode: one thread per (sorted point, level); dim0 hash prime == 1 =>
//           corner pair sits in one aligned 16B block for 75% of ix (and one
//           64B line for 94%). Unified branch: 4 uint4 loads + masked fixup.
//   mlp:    MFMA bf16 16x16x32; writes out[] through the sort permutation.

constexpr int      LVLS   = 16;
constexpr uint32_t TSIZE  = 1u << 19;
constexpr uint32_t TMASK  = TSIZE - 1u;
constexpr uint32_t PRIME1 = 2654435761u;
constexpr uint32_t PRIME2 = 805459861u;
constexpr int      BINS   = 32768;        // 5 bits per dim

struct ResArr { float v[LVLS]; };  // res[l] - 1.0f

typedef __attribute__((ext_vector_type(8))) short short8v;  // 8 bf16 (4 VGPRs)
typedef __attribute__((ext_vector_type(4))) float float4v;  // MFMA 16x16 acc

__device__ inline ushort f2bf(float f) {          // RNE f32 -> bf16
    uint u = __float_as_uint(f);
    u += 0x7fffu + ((u >> 16) & 1u);
    return (ushort)(u >> 16);
}

__device__ inline float2 h2f(uint u) {
    __half2 h = *reinterpret_cast<__half2*>(&u);
    return __half22float2(h);
}

__device__ inline uint pick4(const uint4& b, uint j) {
    const uint lo = (j & 1u) ? b.y : b.x;
    const uint hi = (j & 1u) ? b.w : b.z;
    return (j & 2u) ? hi : lo;
}

__device__ inline uint skey(float X, float Y, float Z) {
    uint kx = (uint)(X * 32.f); kx = kx > 31u ? 31u : kx;
    uint ky = (uint)(Y * 32.f); ky = ky > 31u ? 31u : ky;
    uint kz = (uint)(Z * 32.f); kz = kz > 31u ? 31u : kz;
    return (kz << 10) | (ky << 5) | kx;   // x fastest: big x-extent is free
}

// ---------------- sort: histogram ----------------
__global__ __launch_bounds__(256)
void sort_hist(const float* __restrict__ x, uint* __restrict__ hist, int n)
{
    const int i = blockIdx.x * 256 + threadIdx.x;
    if (i >= n) return;
    atomicAdd(&hist[skey(x[3 * i], x[3 * i + 1], x[3 * i + 2])], 1u);
}

// ---------------- sort: single-block exclusive scan over BINS ----------------
__global__ __launch_bounds__(256)
void sort_scan(const uint* __restrict__ hist, uint* __restrict__ offs)
{
    __shared__ uint part[256];
    const int t = threadIdx.x;
    const int PER = BINS / 256;           // 128
    uint s = 0;
    for (int j = 0; j < PER; ++j) s += hist[t * PER + j];
    part[t] = s;
    __syncthreads();
    for (int d = 1; d < 256; d <<= 1) {
        uint v = (t >= d) ? part[t - d] : 0u;
        __syncthreads();
        part[t] += v;
        __syncthreads();
    }
    uint base = (t == 0) ? 0u : part[t - 1];
    for (int j = 0; j < PER; ++j) {
        const uint h = hist[t * PER + j];
        offs[t * PER + j] = base;
        base += h;
    }
}

// ---------------- sort: scatter ----------------
__global__ __launch_bounds__(256)
void sort_scatter(const float* __restrict__ x, uint* __restrict__ offs,
                  float4* __restrict__ x4s, uint* __restrict__ perm, int n)
{
    const int i = blockIdx.x * 256 + threadIdx.x;
    if (i >= n) return;
    const float X = x[3 * i], Y = x[3 * i + 1], Z = x[3 * i + 2];
    const uint pos = atomicAdd(&offs[skey(X, Y, Z)], 1u);
    x4s[pos] = make_float4(X, Y, Z, 0.f);
    perm[pos] = (uint)i;
}

// ---------------- conv: table -> fp16 pairs (+ optional x pack) ------------
__global__ __launch_bounds__(256)
void ingp_conv(const float* __restrict__ table, uint* __restrict__ tab16,
               const float* __restrict__ x, float4* __restrict__ x4, int n)
{
    const int t = blockIdx.x * 256 + threadIdx.x;
    const int HALF = LVLS * (int)TSIZE / 2;
    if (t < HALF) {
        const float4 v = *reinterpret_cast<const float4*>(table + (size_t)t * 4u);
        __half2 ha = __floats2half2_rn(v.x, v.y);
        __half2 hb = __floats2half2_rn(v.z, v.w);
        uint2 o;
        o.x = *reinterpret_cast<uint*>(&ha);
        o.y = *reinterpret_cast<uint*>(&hb);
        *reinterpret_cast<uint2*>(tab16 + (size_t)t * 2u) = o;
    }
    if (t < n)
        x4[t] = make_float4(x[3 * t + 0], x[3 * t + 1], x[3 * t + 2], 0.f);
}

// ---------------- prep: weight transpose + bf16 cast ----------------
__global__ __launch_bounds__(256)
void ingp_prep(const float* __restrict__ w1, const float* __restrict__ w2,
               const float* __restrict__ w3,
               ushort* __restrict__ w1t, ushort* __restrict__ w2t,
               ushort* __restrict__ w3t)
{
    const int t = blockIdx.x * 256 + threadIdx.x;
    if (t < 2048) {
        const int nn = t >> 5, k = t & 31;
        w1t[t] = f2bf(w1[k * 64 + nn]);
    } else if (t < 2048 + 4096) {
        const int q = t - 2048;
        const int nn = q >> 6, k = q & 63;
        w2t[q] = f2bf(w2[k * 64 + nn]);
    } else if (t < 2048 + 4096 + 1024) {
        const int q = t - 6144;
        const int nn = q >> 6, k = q & 63;
        w3t[q] = (nn < 3) ? f2bf(w3[k * 3 + nn]) : (ushort)0;
    }
}

// ---------------- encode: fp16 table, block-pair loads ----------------
__global__ __launch_bounds__(256, 8)
void ingp_encode_f16(const float4* __restrict__ x4,
                     const uint* __restrict__ tab16,
                     uint* __restrict__ feat, int n, ResArr res)
{
    const int i = blockIdx.x * 256 + threadIdx.x;
    const int l = blockIdx.y;
    if (i >= n) return;

    const float4 xp = x4[i];
    const float rm1 = res.v[l];
    const float px = xp.x * rm1, py = xp.y * rm1, pz = xp.z * rm1;
    const float fpx = floorf(px), fpy = floorf(py), fpz = floorf(pz);
    const float fx = px - fpx, fy = py - fpy, fz = pz - fpz;
    const uint32_t ix = (uint32_t)fpx;
    const uint32_t iy = (uint32_t)fpy;
    const uint32_t iz = (uint32_t)fpz;
    const uint32_t hy0 = iy * PRIME1, hy1 = (iy + 1u) * PRIME1;
    const uint32_t hz0 = iz * PRIME2, hz1 = (iz + 1u) * PRIME2;
    const uint* tl = tab16 + (size_t)l * (size_t)TSIZE;

    uint32_t h0[4], h1[4];
    #pragma unroll
    for (int p = 0; p < 4; ++p) {
        const uint32_t bj = (p >> 1) & 1, bk = p & 1;
        const uint32_t hyz = (bj ? hy1 : hy0) ^ (bk ? hz1 : hz0);
        h0[p] = (ix ^ hyz) & TMASK;
        h1[p] = ((ix + 1u) ^ hyz) & TMASK;
    }

    // always: one aligned 16B block per (bj,bk) covers e0 (and e1 when
    // d = ix^(ix+1) <= 3, i.e. 75% of ix). Masked scalar fixup otherwise.
    const bool fast = (ix & 3u) != 3u;
    uint e0[4], e1[4];
    #pragma unroll
    for (int p = 0; p < 4; ++p) {
        const uint32_t base = h0[p] & ~3u;
        const uint4 blk = *reinterpret_cast<const uint4*>(tl + base);
        e0[p] = pick4(blk, h0[p] & 3u);
        e1[p] = fast ? pick4(blk, h1[p] & 3u) : 0u;
    }
    if (!fast) {
        #pragma unroll
        for (int p = 0; p < 4; ++p) e1[p] = tl[h1[p]];
    }

    const float gx0 = 1.f - fx, gx1 = fx;
    float a0 = 0.f, a1 = 0.f;
    #pragma unroll
    for (int p = 0; p < 4; ++p) {
        const int bj = (p >> 1) & 1, bk = p & 1;
        const float wyz = (bj ? fy : 1.f - fy) * (bk ? fz : 1.f - fz);
        const float w0 = wyz * gx0, w1 = wyz * gx1;
        const float2 c0 = h2f(e0[p]);
        const float2 c1 = h2f(e1[p]);
        a0 = fmaf(w0, c0.x, a0);
        a1 = fmaf(w0, c0.y, a1);
        a0 = fmaf(w1, c1.x, a0);
        a1 = fmaf(w1, c1.y, a1);
    }
    feat[(size_t)l * n + i] = (uint)f2bf(a0) | ((uint)f2bf(a1) << 16);
}

// ---------------- mid fallback: f32 table, paired-corner loads ------------
__global__ __launch_bounds__(256, 8)
void ingp_encode(const float* __restrict__ x,
                 const float* __restrict__ table,
                 uint* __restrict__ feat, int n, ResArr res)
{
    const int i = blockIdx.x * 256 + threadIdx.x;
    const int l = blockIdx.y;
    if (i >= n) return;
    const float xx = x[3 * i + 0], xy = x[3 * i + 1], xz = x[3 * i + 2];
    const float rm1 = res.v[l];
    const float px = xx * rm1, py = xy * rm1, pz = xz * rm1;
    const float fpx = floorf(px), fpy = floorf(py), fpz = floorf(pz);
    const float fx = px - fpx, fy = py - fpy, fz = pz - fpz;
    const uint32_t ix = (uint32_t)fpx, iy = (uint32_t)fpy, iz = (uint32_t)fpz;
    const uint32_t hy0 = iy * PRIME1, hy1 = (iy + 1u) * PRIME1;
    const uint32_t hz0 = iz * PRIME2, hz1 = (iz + 1u) * PRIME2;
    const float* tl = table + (size_t)l * (size_t)TSIZE * 2u;

    uint32_t idx0[4], idx1[4];
    #pragma unroll
    for (int p = 0; p < 4; ++p) {
        const uint32_t bj = (p >> 1) & 1, bk = p & 1;
        const uint32_t hyz = (bj ? hy1 : hy0) ^ (bk ? hz1 : hz0);
        idx0[p] = (ix ^ hyz) & TMASK;
        idx1[p] = ((ix + 1u) ^ hyz) & TMASK;
    }
    float2 c0[4], c1[4];
    if ((ix & 1u) == 0u) {
        #pragma unroll
        for (int p = 0; p < 4; ++p) {
            const uint32_t base = idx0[p] & ~1u;
            const float4 q = *reinterpret_cast<const float4*>(tl + (size_t)base * 2u);
            if (idx0[p] & 1u) { c0[p] = make_float2(q.z, q.w); c1[p] = make_float2(q.x, q.y); }
            else              { c0[p] = make_float2(q.x, q.y); c1[p] = make_float2(q.z, q.w); }
        }
    } else {
        #pragma unroll
        for (int p = 0; p < 4; ++p) {
            c0[p] = *reinterpret_cast<const float2*>(tl + (size_t)idx0[p] * 2u);
            c1[p] = *reinterpret_cast<const float2*>(tl + (size_t)idx1[p] * 2u);
        }
    }
    const float gx0 = 1.f - fx, gx1 = fx;
    float a0 = 0.f, a1 = 0.f;
    #pragma unroll
    for (int p = 0; p < 4; ++p) {
        const int bj = (p >> 1) & 1, bk = p & 1;
        const float wyz = (bj ? fy : 1.f - fy) * (bk ? fz : 1.f - fz);
        const float w0 = wyz * gx0, w1 = wyz * gx1;
        a0 = fmaf(w0, c0[p].x, a0);
        a1 = fmaf(w0, c0[p].y, a1);
        a0 = fmaf(w1, c1[p].x, a0);
        a1 = fmaf(w1, c1[p].y, a1);
    }
    feat[(size_t)l * n + i] = (uint)f2bf(a0) | ((uint)f2bf(a1) << 16);
}

// ---------------- Kernel B: MFMA MLP (optional output permutation) --------
__global__ __launch_bounds__(256)
void ingp_mlp_mfma(const uint* __restrict__ feat,
                   const ushort* __restrict__ w1t,
                   const ushort* __restrict__ w2t,
                   const ushort* __restrict__ w3t,
                   const float* __restrict__ b1,
                   const float* __restrict__ b2,
                   const float* __restrict__ b3,
                   const uint* __restrict__ perm,
                   float* __restrict__ out, int n)
{
    __shared__ ushort s_h[4][64][72];
    const int tid = threadIdx.x;
    const int wv = tid >> 6;
    const int ln = tid & 63;
    const int lm = ln & 15;
    const int lk = ln >> 4;
    const int base = blockIdx.x * 256 + wv * 64;

    short8v a1[4];
    #pragma unroll
    for (int mt = 0; mt < 4; ++mt) {
        int pt = base + mt * 16 + lm;
        pt = pt < n ? pt : (n - 1);
        union { uint u[4]; short8v v; } c;
        #pragma unroll
        for (int j = 0; j < 4; ++j)
            c.u[j] = feat[(size_t)(lk * 4 + j) * (size_t)n + pt];
        a1[mt] = c.v;
    }

    float4v acc[4][4];
    #pragma unroll
    for (int nt = 0; nt < 4; ++nt) {
        const float bv = b1[nt * 16 + lm];
        #pragma unroll
        for (int mt = 0; mt < 4; ++mt)
            acc[mt][nt] = (float4v){bv, bv, bv, bv};
    }
    #pragma unroll
    for (int nt = 0; nt < 4; ++nt) {
        const short8v bfr = *(const short8v*)(w1t + (nt * 16 + lm) * 32 + lk * 8);
        #pragma unroll
        for (int mt = 0; mt < 4; ++mt)
            acc[mt][nt] = __builtin_amdgcn_mfma_f32_16x16x32_bf16(
                a1[mt], bfr, acc[mt][nt], 0, 0, 0);
    }
    #pragma unroll
    for (int mt = 0; mt < 4; ++mt)
        #pragma unroll
        for (int nt = 0; nt < 4; ++nt)
            #pragma unroll
            for (int r = 0; r < 4; ++r)
                s_h[wv][mt * 16 + lk * 4 + r][nt * 16 + lm] =
                    f2bf(fmaxf(acc[mt][nt][r], 0.f));
    __syncthreads();

    float4v acc2[4][4];
    #pragma unroll
    for (int nt = 0; nt < 4; ++nt) {
        const float bv = b2[nt * 16 + lm];
        #pragma unroll
        for (int mt = 0; mt < 4; ++mt)
            acc2[mt][nt] = (float4v){bv, bv, bv, bv};
    }
    #pragma unroll
    for (int ks = 0; ks < 2; ++ks) {
        short8v a2[4];
        #pragma unroll
        for (int mt = 0; mt < 4; ++mt)
            a2[mt] = *(const short8v*)&s_h[wv][mt * 16 + lm][ks * 32 + lk * 8];
        #pragma unroll
        for (int nt = 0; nt < 4; ++nt) {
            const short8v bfr =
                *(const short8v*)(w2t + (nt * 16 + lm) * 64 + ks * 32 + lk * 8);
            #pragma unroll
            for (int mt = 0; mt < 4; ++mt)
                acc2[mt][nt] = __builtin_amdgcn_mfma_f32_16x16x32_bf16(
                    a2[mt], bfr, acc2[mt][nt], 0, 0, 0);
        }
    }
    __syncthreads();
    #pragma unroll
    for (int mt = 0; mt < 4; ++mt)
        #pragma unroll
        for (int nt = 0; nt < 4; ++nt)
            #pragma unroll
            for (int r = 0; r < 4; ++r)
                s_h[wv][mt * 16 + lk * 4 + r][nt * 16 + lm] =
                    f2bf(fmaxf(acc2[mt][nt][r], 0.f));
    __syncthreads();

    float4v acc3[4];
    const float bv3 = (lm < 3) ? b3[lm] : 0.f;
    #pragma unroll
    for (int mt = 0; mt < 4; ++mt)
        acc3[mt] = (float4v){bv3, bv3, bv3, bv3};
    #pragma unroll
    for (int ks = 0; ks < 2; ++ks) {
        const short8v bfr = *(const short8v*)(w3t + lm * 64 + ks * 32 + lk * 8);
        #pragma unroll
        for (int mt = 0; mt < 4; ++mt) {
            const short8v a3 =
                *(const short8v*)&s_h[wv][mt * 16 + lm][ks * 32 + lk * 8];
            acc3[mt] = __builtin_amdgcn_mfma_f32_16x16x32_bf16(
                a3, bfr, acc3[mt], 0, 0, 0);
        }
    }
    if (lm < 3) {
        #pragma unroll
        for (int mt = 0; mt < 4; ++mt)
            #pragma unroll
            for (int r = 0; r < 4; ++r) {
                const int pt = base + mt * 16 + lk * 4 + r;
                if (pt < n) {
                    const uint o = perm ? perm[pt] : (uint)pt;
                    out[o * 3u + lm] = 1.f / (1.f + __expf(-acc3[mt][r]));
                }
            }
    }
}

// ---------------- last fallback: f32 MLP + h2 encode ----------------
__global__ __launch_bounds__(256)
void ingp_mlp(const __half2* __restrict__ feat16,
              const float* __restrict__ w1, const float* __restrict__ b1,
              const float* __restrict__ w2, const float* __restrict__ b2,
              const float* __restrict__ w3, const float* __restrict__ b3,
              float* __restrict__ out, int n)
{
    __shared__ float s_w1[32 * 64];
    __shared__ float s_w2[64 * 64];
    __shared__ float s_w3[64 * 3];
    __shared__ float s_b1[64];
    __shared__ float s_b2[64];
    __shared__ float s_b3[3];
    for (int t = threadIdx.x; t < 32 * 64; t += 256) s_w1[t] = w1[t];
    for (int t = threadIdx.x; t < 64 * 64; t += 256) s_w2[t] = w2[t];
    for (int t = threadIdx.x; t < 64 * 3;  t += 256) s_w3[t] = w3[t];
    if (threadIdx.x < 64) { s_b1[threadIdx.x] = b1[threadIdx.x]; s_b2[threadIdx.x] = b2[threadIdx.x]; }
    if (threadIdx.x < 3) s_b3[threadIdx.x] = b3[threadIdx.x];
    __syncthreads();
    const int i = blockIdx.x * 256 + threadIdx.x;
    if (i >= n) return;
    float feat[32];
    #pragma unroll
    for (int l = 0; l < LVLS; ++l) {
        const float2 f = __half22float2(feat16[(size_t)l * n + i]);
        feat[2 * l + 0] = f.x;
        feat[2 * l + 1] = f.y;
    }
    float h1[64];
    #pragma unroll
    for (int j = 0; j < 64; ++j) h1[j] = s_b1[j];
    #pragma unroll
    for (int k = 0; k < 32; ++k) {
        const float fv = feat[k];
        #pragma unroll
        for (int j = 0; j < 64; ++j) h1[j] = fmaf(fv, s_w1[k * 64 + j], h1[j]);
    }
    #pragma unroll
    for (int j = 0; j < 64; ++j) h1[j] = fmaxf(h1[j], 0.f);
    float h2[64];
    #pragma unroll
    for (int j = 0; j < 64; ++j) h2[j] = s_b2[j];
    #pragma unroll
    for (int k = 0; k < 64; ++k) {
        const float hv = h1[k];
        #pragma unroll
        for (int j = 0; j < 64; ++j) h2[j] = fmaf(hv, s_w2[k * 64 + j], h2[j]);
    }
    #pragma unroll
    for (int j = 0; j < 64; ++j) h2[j] = fmaxf(h2[j], 0.f);
    float o0 = s_b3[0], o1 = s_b3[1], o2 = s_b3[2];
    #pragma unroll
    for (int j = 0; j < 64; ++j) {
        const float hv = h2[j];
        o0 = fmaf(hv, s_w3[j * 3 + 0], o0);
        o1 = fmaf(hv, s_w3[j * 3 + 1], o1);
        o2 = fmaf(hv, s_w3[j * 3 + 2], o2);
    }
    out[3 * i + 0] = 1.f / (1.f + __expf(-o0));
    out[3 * i + 1] = 1.f / (1.f + __expf(-o1));
    out[3 * i + 2] = 1.f / (1.f + __expf(-o2));
}

__global__ __launch_bounds__(256, 8)
void ingp_encode_h2(const float* __restrict__ x,
                    const float* __restrict__ table,
                    __half2* __restrict__ feat16, int n, ResArr res)
{
    const int i = blockIdx.x * 256 + threadIdx.x;
    const int l = blockIdx.y;
    if (i >= n) return;
    const float xx = x[3 * i + 0], xy = x[3 * i + 1], xz = x[3 * i + 2];
    const float rm1 = res.v[l];
    const float px = xx * rm1, py = xy * rm1, pz = xz * rm1;
    const float fpx = floorf(px), fpy = floorf(py), fpz = floorf(pz);
    const float fx = px - fpx, fy = py - fpy, fz = pz - fpz;
    const uint32_t ix = (uint32_t)fpx, iy = (uint32_t)fpy, iz = (uint32_t)fpz;
    const uint32_t hy0 = iy * PRIME1, hy1 = (iy + 1u) * PRIME1;
    const uint32_t hz0 = iz * PRIME2, hz1 = (iz + 1u) * PRIME2;
    const float* tl = table + (size_t)l * (size_t)TSIZE * 2u;
    float a0 = 0.f, a1 = 0.f;
    #pragma unroll
    for (int c = 0; c < 8; ++c) {
        const int bi = (c >> 2) & 1, bj = (c >> 1) & 1, bk = c & 1;
        const uint32_t h = ((ix + (uint32_t)bi) ^ (bj ? hy1 : hy0) ^ (bk ? hz1 : hz0)) & TMASK;
        const float2 tv = *reinterpret_cast<const float2*>(tl + (size_t)h * 2u);
        const float w = (bi ? fx : 1.f - fx) * (bj ? fy : 1.f - fy) * (bk ? fz : 1.f - fz);
        a0 = fmaf(w, tv.x, a0);
        a1 = fmaf(w, tv.y, a1);
    }
    feat16[(size_t)l * n + i] = __floats2half2_rn(a0, a1);
}

extern "C" void kernel_launch(void* const* d_in, const int* in_sizes, int n_in,
                              void* d_out, int out_size, void* d_ws, size_t ws_size,
                              hipStream_t stream)
{
    const float* x     = (const float*)d_in[0];
    const float* table = (const float*)d_in[1];
    const float* w1    = (const float*)d_in[2];
    const float* b1    = (const float*)d_in[3];
    const float* w2    = (const float*)d_in[4];
    const float* b2    = (const float*)d_in[5];
    const float* w3    = (const float*)d_in[6];
    const float* b3    = (const float*)d_in[7];
    float* out = (float*)d_out;

    const int n = in_sizes[0] / 3;

    ResArr res;
    const double S = (double)1.3819061f;
    double p = 1.0;
    for (int l = 0; l < LVLS; ++l) {
        res.v[l] = (float)floor(16.0 * p) - 1.0f;
        p *= S;
    }

    const int gb = (n + 255) / 256;
    const size_t feat_bytes  = (size_t)LVLS * (size_t)n * 4u;        // 32 MB
    const size_t tab16_bytes = (size_t)LVLS * (size_t)TSIZE * 4u;    // 33.5 MB
    const size_t x4_bytes    = (size_t)n * 16u;                      // 8 MB
    const size_t perm_bytes  = (size_t)n * 4u;                       // 2 MB
    const size_t hist_bytes  = (size_t)BINS * 4u;                    // 128 KB

    const size_t off_tab16 = 16384;
    const size_t off_feat  = off_tab16 + tab16_bytes;
    const size_t off_x4    = off_feat + feat_bytes;
    const size_t off_perm  = off_x4 + x4_bytes;
    const size_t off_hist  = off_perm + perm_bytes;
    const size_t off_offs  = off_hist + hist_bytes;
    const size_t need_sort = off_offs + hist_bytes;
    const size_t need_full = off_x4 + x4_bytes;     // round-5 path
    const size_t need_mid  = 16384 + feat_bytes;

    if (ws_size >= need_sort) {
        ushort* w1t  = (ushort*)d_ws;
        ushort* w2t  = w1t + 2048;
        ushort* w3t  = w2t + 4096;
        uint*   tab16 = (uint*)((char*)d_ws + off_tab16);
        uint*   feat  = (uint*)((char*)d_ws + off_feat);
        float4* x4s   = (float4*)((char*)d_ws + off_x4);
        uint*   perm  = (uint*)((char*)d_ws + off_perm);
        uint*   hist  = (uint*)((char*)d_ws + off_hist);
        uint*   offs  = (uint*)((char*)d_ws + off_offs);

        hipMemsetAsync(hist, 0, hist_bytes, stream);
        sort_hist<<<gb, 256, 0, stream>>>(x, hist, n);
        sort_scan<<<1, 256, 0, stream>>>(hist, offs);
        sort_scatter<<<gb, 256, 0, stream>>>(x, offs, x4s, perm, n);

        const int conv_threads = LVLS * (int)TSIZE / 2;
        ingp_conv<<<(conv_threads + 255) / 256, 256, 0, stream>>>(
            table, tab16, x, (float4*)nullptr, 0);
        ingp_prep<<<28, 256, 0, stream>>>(w1, w2, w3, w1t, w2t, w3t);
        dim3 gridA(gb, LVLS);
        ingp_encode_f16<<<gridA, 256, 0, stream>>>(x4s, tab16, feat, n, res);
        ingp_mlp_mfma<<<gb, 256, 0, stream>>>(feat, w1t, w2t, w3t,
                                              b1, b2, b3, perm, out, n);
    } else if (ws_size >= need_full) {
        ushort* w1t  = (ushort*)d_ws;
        ushort* w2t  = w1t + 2048;
        ushort* w3t  = w2t + 4096;
        uint*   tab16 = (uint*)((char*)d_ws + off_tab16);
        uint*   feat  = (uint*)((char*)d_ws + off_feat);
        float4* x4    = (float4*)((char*)d_ws + off_x4);

        const int conv_threads = LVLS * (int)TSIZE / 2;
        ingp_conv<<<(conv_threads + 255) / 256, 256, 0, stream>>>(
            table, tab16, x, x4, n);
        ingp_prep<<<28, 256, 0, stream>>>(w1, w2, w3, w1t, w2t, w3t);
        dim3 gridA(gb, LVLS);
        ingp_encode_f16<<<gridA, 256, 0, stream>>>(x4, tab16, feat, n, res);
        ingp_mlp_mfma<<<gb, 256, 0, stream>>>(feat, w1t, w2t, w3t,
                                              b1, b2, b3, (const uint*)nullptr,
                                              out, n);
    } else if (ws_size >= need_mid) {
        ushort* w1t = (ushort*)d_ws;
        ushort* w2t = w1t + 2048;
        ushort* w3t = w2t + 4096;
        uint*   feat = (uint*)((char*)d_ws + 16384);
        ingp_prep<<<28, 256, 0, stream>>>(w1, w2, w3, w1t, w2t, w3t);
        dim3 gridA(gb, LVLS);
        ingp_encode<<<gridA, 256, 0, stream>>>(x, table, feat, n, res);
        ingp_mlp_mfma<<<gb, 256, 0, stream>>>(feat, w1t, w2t, w3t,
                                              b1, b2, b3, (const uint*)nullptr,
                                              out, n);
    } else {
        dim3 gridA(gb, LVLS);
        ingp_encode_h2<<<gridA, 256, 0, stream>>>(x, table, (__half2*)d_ws, n, res);
        ingp_mlp<<<gb, 256, 0, stream>>>((const __half2*)d_ws,
                                         w1, b1, w2, b2, w3, b3, out, n);
    }
}

// Round 7
// 235.028 us; speedup vs baseline: 1.0152x; 1.0152x over previous
//
#include <hip/hip_runtime.h>
#include <hip/hip_fp16.h>
#include <math.h>

// Instant-NGP forward:
//   sort:   bucket points by quantized (z,y,x) key (32768 bins); parallel
//           3-kernel scan. Waves then cover small spatial boxes -> line sharing.
//   dense:  levels 0-6 un-hashed into dense [R^3] fp16 tables (8.8 MB) -> corner
//           pair is ALWAYS adjacent (+0/+1), tables L1/L2-resident.
//   conv:   levels 7-15 f32 -> fp16-pair hash tables (4B/entry).
//   encode: one thread per (sorted point, level); dense path for l<7, hash
//           paired-block path (dim0 prime == 1) for l>=7.
//   mlp:    MFMA bf16 16x16x32; writes out[] through the sort permutation.

constexpr int      LVLS   = 16;
constexpr int      NDENSE = 7;            // levels 0..6 dense
constexpr uint32_t TSIZE  = 1u << 19;
constexpr uint32_t TMASK  = TSIZE - 1u;
constexpr uint32_t PRIME1 = 2654435761u;
constexpr uint32_t PRIME2 = 805459861u;
constexpr int      BINS   = 32768;        // 5 bits per dim

struct ResArr { float v[LVLS]; };         // res[l] - 1.0f
struct DenseDims { uint R[NDENSE]; uint off[NDENSE]; uint total; };

typedef __attribute__((ext_vector_type(8))) short short8v;  // 8 bf16
typedef __attribute__((ext_vector_type(4))) float float4v;  // MFMA acc

__device__ inline ushort f2bf(float f) {
    uint u = __float_as_uint(f);
    u += 0x7fffu + ((u >> 16) & 1u);
    return (ushort)(u >> 16);
}

__device__ inline float2 h2f(uint u) {
    __half2 h = *reinterpret_cast<__half2*>(&u);
    return __half22float2(h);
}

__device__ inline uint pick4(const uint4& b, uint j) {
    const uint lo = (j & 1u) ? b.y : b.x;
    const uint hi = (j & 1u) ? b.w : b.z;
    return (j & 2u) ? hi : lo;
}

__device__ inline uint skey(float X, float Y, float Z) {
    uint kx = (uint)(X * 32.f); kx = kx > 31u ? 31u : kx;
    uint ky = (uint)(Y * 32.f); ky = ky > 31u ? 31u : ky;
    uint kz = (uint)(Z * 32.f); kz = kz > 31u ? 31u : kz;
    return (kz << 10) | (ky << 5) | kx;
}

// ---------------- sort: histogram ----------------
__global__ __launch_bounds__(256)
void sort_hist(const float* __restrict__ x, uint* __restrict__ hist, int n)
{
    const int i = blockIdx.x * 256 + threadIdx.x;
    if (i >= n) return;
    atomicAdd(&hist[skey(x[3 * i], x[3 * i + 1], x[3 * i + 2])], 1u);
}

// ---------------- sort: parallel scan (3 kernels) ----------------
__global__ __launch_bounds__(256)
void scan1(const uint* __restrict__ hist, uint* __restrict__ bsum)
{
    __shared__ uint s[256];
    const int t = threadIdx.x;
    s[t] = hist[blockIdx.x * 256 + t];
    __syncthreads();
    for (int d = 128; d > 0; d >>= 1) {
        if (t < d) s[t] += s[t + d];
        __syncthreads();
    }
    if (t == 0) bsum[blockIdx.x] = s[0];
}

__global__ __launch_bounds__(128)
void scan2(uint* __restrict__ bsum)          // exclusive scan of 128 values
{
    __shared__ uint s[128];
    const int t = threadIdx.x;
    const uint v = bsum[t];
    s[t] = v;
    __syncthreads();
    for (int d = 1; d < 128; d <<= 1) {
        uint add = (t >= d) ? s[t - d] : 0u;
        __syncthreads();
        s[t] += add;
        __syncthreads();
    }
    bsum[t] = s[t] - v;                      // exclusive
}

__global__ __launch_bounds__(256)
void scan3(const uint* __restrict__ hist, const uint* __restrict__ bsum,
           uint* __restrict__ offs)
{
    __shared__ uint s[256];
    const int t = threadIdx.x;
    const int g = blockIdx.x * 256 + t;
    const uint v = hist[g];
    s[t] = v;
    __syncthreads();
    for (int d = 1; d < 256; d <<= 1) {
        uint add = (t >= d) ? s[t - d] : 0u;
        __syncthreads();
        s[t] += add;
        __syncthreads();
    }
    offs[g] = bsum[blockIdx.x] + s[t] - v;   // exclusive
}

// ---------------- sort: scatter ----------------
__global__ __launch_bounds__(256)
void sort_scatter(const float* __restrict__ x, uint* __restrict__ offs,
                  float4* __restrict__ x4s, uint* __restrict__ perm, int n)
{
    const int i = blockIdx.x * 256 + threadIdx.x;
    if (i >= n) return;
    const float X = x[3 * i], Y = x[3 * i + 1], Z = x[3 * i + 2];
    const uint pos = atomicAdd(&offs[skey(X, Y, Z)], 1u);
    x4s[pos] = make_float4(X, Y, Z, 0.f);
    perm[pos] = (uint)i;
}

// ---------------- dense build: levels 0..6 un-hashed ----------------
__global__ __launch_bounds__(256)
void dense_build(const float* __restrict__ table, uint* __restrict__ dense,
                 DenseDims dd)
{
    const uint g = blockIdx.x * 256 + threadIdx.x;
    if (g >= dd.total) return;
    int l = 0;
    #pragma unroll
    for (int j = 1; j < NDENSE; ++j) if (g >= dd.off[j]) l = j;
    const uint c = g - dd.off[l];
    const uint R = dd.R[l];
    const uint ixx = c % R;
    const uint tq  = c / R;
    const uint iyy = tq % R;
    const uint izz = tq / R;
    const uint h = (ixx ^ (iyy * PRIME1) ^ (izz * PRIME2)) & TMASK;
    const float2 v = *reinterpret_cast<const float2*>(
        table + ((size_t)l * TSIZE + h) * 2u);
    __half2 hv = __floats2half2_rn(v.x, v.y);
    dense[g] = *reinterpret_cast<uint*>(&hv);
}

// ---------------- conv: hash levels 7..15 -> fp16 pairs ----------------
__global__ __launch_bounds__(256)
void ingp_conv9(const float* __restrict__ table, uint* __restrict__ tab16)
{
    const int t = blockIdx.x * 256 + threadIdx.x;
    const int HALF = (LVLS - NDENSE) * (int)TSIZE / 2;
    if (t >= HALF) return;
    const float4 v = *reinterpret_cast<const float4*>(
        table + (size_t)NDENSE * TSIZE * 2u + (size_t)t * 4u);
    __half2 ha = __floats2half2_rn(v.x, v.y);
    __half2 hb = __floats2half2_rn(v.z, v.w);
    uint2 o;
    o.x = *reinterpret_cast<uint*>(&ha);
    o.y = *reinterpret_cast<uint*>(&hb);
    *reinterpret_cast<uint2*>(tab16 + (size_t)t * 2u) = o;
}

// ---------------- prep: weight transpose + bf16 cast ----------------
__global__ __launch_bounds__(256)
void ingp_prep(const float* __restrict__ w1, const float* __restrict__ w2,
               const float* __restrict__ w3,
               ushort* __restrict__ w1t, ushort* __restrict__ w2t,
               ushort* __restrict__ w3t)
{
    const int t = blockIdx.x * 256 + threadIdx.x;
    if (t < 2048) {
        const int nn = t >> 5, k = t & 31;
        w1t[t] = f2bf(w1[k * 64 + nn]);
    } else if (t < 2048 + 4096) {
        const int q = t - 2048;
        const int nn = q >> 6, k = q & 63;
        w2t[q] = f2bf(w2[k * 64 + nn]);
    } else if (t < 2048 + 4096 + 1024) {
        const int q = t - 6144;
        const int nn = q >> 6, k = q & 63;
        w3t[q] = (nn < 3) ? f2bf(w3[k * 3 + nn]) : (ushort)0;
    }
}

// ---------------- encode: dense (l<7) or fp16 hash (l>=7) ----------------
__global__ __launch_bounds__(256, 8)
void ingp_encode_ds(const float4* __restrict__ x4,
                    const uint* __restrict__ tab16,
                    const uint* __restrict__ dense,
                    uint* __restrict__ feat, int n, ResArr res, DenseDims dd)
{
    const int i = blockIdx.x * 256 + threadIdx.x;
    const int l = blockIdx.y;
    if (i >= n) return;

    const float4 xp = x4[i];
    const float rm1 = res.v[l];
    const float px = xp.x * rm1, py = xp.y * rm1, pz = xp.z * rm1;
    const float fpx = floorf(px), fpy = floorf(py), fpz = floorf(pz);
    const float fx = px - fpx, fy = py - fpy, fz = pz - fpz;
    const uint32_t ix = (uint32_t)fpx;
    const uint32_t iy = (uint32_t)fpy;
    const uint32_t iz = (uint32_t)fpz;

    uint e0[4], e1[4];
    if (l < NDENSE) {
        const uint R = dd.R[l];
        const uint* dl = dense + dd.off[l];
        #pragma unroll
        for (int p = 0; p < 4; ++p) {
            const uint bj = (p >> 1) & 1u, bk = p & 1u;
            const uint row = ((iz + bk) * R + (iy + bj)) * R + ix;
            e0[p] = dl[row];
            e1[p] = dl[row + 1];
        }
    } else {
        const uint32_t hy0 = iy * PRIME1, hy1 = (iy + 1u) * PRIME1;
        const uint32_t hz0 = iz * PRIME2, hz1 = (iz + 1u) * PRIME2;
        const uint* tl = tab16 + (size_t)(l - NDENSE) * (size_t)TSIZE;
        uint32_t h0[4], h1[4];
        #pragma unroll
        for (int p = 0; p < 4; ++p) {
            const uint32_t bj = (p >> 1) & 1, bk = p & 1;
            const uint32_t hyz = (bj ? hy1 : hy0) ^ (bk ? hz1 : hz0);
            h0[p] = (ix ^ hyz) & TMASK;
            h1[p] = ((ix + 1u) ^ hyz) & TMASK;
        }
        const bool fast = (ix & 3u) != 3u;
        #pragma unroll
        for (int p = 0; p < 4; ++p) {
            const uint32_t base = h0[p] & ~3u;
            const uint4 blk = *reinterpret_cast<const uint4*>(tl + base);
            e0[p] = pick4(blk, h0[p] & 3u);
            e1[p] = fast ? pick4(blk, h1[p] & 3u) : 0u;
        }
        if (!fast) {
            #pragma unroll
            for (int p = 0; p < 4; ++p) e1[p] = tl[h1[p]];
        }
    }

    const float gx0 = 1.f - fx, gx1 = fx;
    float a0 = 0.f, a1 = 0.f;
    #pragma unroll
    for (int p = 0; p < 4; ++p) {
        const int bj = (p >> 1) & 1, bk = p & 1;
        const float wyz = (bj ? fy : 1.f - fy) * (bk ? fz : 1.f - fz);
        const float w0 = wyz * gx0, w1 = wyz * gx1;
        const float2 c0 = h2f(e0[p]);
        const float2 c1 = h2f(e1[p]);
        a0 = fmaf(w0, c0.x, a0);
        a1 = fmaf(w0, c0.y, a1);
        a0 = fmaf(w1, c1.x, a0);
        a1 = fmaf(w1, c1.y, a1);
    }
    feat[(size_t)l * n + i] = (uint)f2bf(a0) | ((uint)f2bf(a1) << 16);
}

// ---------------- mid fallback: f32 table, paired-corner loads ------------
__global__ __launch_bounds__(256, 8)
void ingp_encode(const float* __restrict__ x,
                 const float* __restrict__ table,
                 uint* __restrict__ feat, int n, ResArr res)
{
    const int i = blockIdx.x * 256 + threadIdx.x;
    const int l = blockIdx.y;
    if (i >= n) return;
    const float xx = x[3 * i + 0], xy = x[3 * i + 1], xz = x[3 * i + 2];
    const float rm1 = res.v[l];
    const float px = xx * rm1, py = xy * rm1, pz = xz * rm1;
    const float fpx = floorf(px), fpy = floorf(py), fpz = floorf(pz);
    const float fx = px - fpx, fy = py - fpy, fz = pz - fpz;
    const uint32_t ix = (uint32_t)fpx, iy = (uint32_t)fpy, iz = (uint32_t)fpz;
    const uint32_t hy0 = iy * PRIME1, hy1 = (iy + 1u) * PRIME1;
    const uint32_t hz0 = iz * PRIME2, hz1 = (iz + 1u) * PRIME2;
    const float* tl = table + (size_t)l * (size_t)TSIZE * 2u;

    uint32_t idx0[4], idx1[4];
    #pragma unroll
    for (int p = 0; p < 4; ++p) {
        const uint32_t bj = (p >> 1) & 1, bk = p & 1;
        const uint32_t hyz = (bj ? hy1 : hy0) ^ (bk ? hz1 : hz0);
        idx0[p] = (ix ^ hyz) & TMASK;
        idx1[p] = ((ix + 1u) ^ hyz) & TMASK;
    }
    float2 c0[4], c1[4];
    if ((ix & 1u) == 0u) {
        #pragma unroll
        for (int p = 0; p < 4; ++p) {
            const uint32_t base = idx0[p] & ~1u;
            const float4 q = *reinterpret_cast<const float4*>(tl + (size_t)base * 2u);
            if (idx0[p] & 1u) { c0[p] = make_float2(q.z, q.w); c1[p] = make_float2(q.x, q.y); }
            else              { c0[p] = make_float2(q.x, q.y); c1[p] = make_float2(q.z, q.w); }
        }
    } else {
        #pragma unroll
        for (int p = 0; p < 4; ++p) {
            c0[p] = *reinterpret_cast<const float2*>(tl + (size_t)idx0[p] * 2u);
            c1[p] = *reinterpret_cast<const float2*>(tl + (size_t)idx1[p] * 2u);
        }
    }
    const float gx0 = 1.f - fx, gx1 = fx;
    float a0 = 0.f, a1 = 0.f;
    #pragma unroll
    for (int p = 0; p < 4; ++p) {
        const int bj = (p >> 1) & 1, bk = p & 1;
        const float wyz = (bj ? fy : 1.f - fy) * (bk ? fz : 1.f - fz);
        const float w0 = wyz * gx0, w1 = wyz * gx1;
        a0 = fmaf(w0, c0[p].x, a0);
        a1 = fmaf(w0, c0[p].y, a1);
        a0 = fmaf(w1, c1[p].x, a0);
        a1 = fmaf(w1, c1[p].y, a1);
    }
    feat[(size_t)l * n + i] = (uint)f2bf(a0) | ((uint)f2bf(a1) << 16);
}

// ---------------- Kernel B: MFMA MLP (optional output permutation) --------
__global__ __launch_bounds__(256)
void ingp_mlp_mfma(const uint* __restrict__ feat,
                   const ushort* __restrict__ w1t,
                   const ushort* __restrict__ w2t,
                   const ushort* __restrict__ w3t,
                   const float* __restrict__ b1,
                   const float* __restrict__ b2,
                   const float* __restrict__ b3,
                   const uint* __restrict__ perm,
                   float* __restrict__ out, int n)
{
    __shared__ ushort s_h[4][64][72];
    const int tid = threadIdx.x;
    const int wv = tid >> 6;
    const int ln = tid & 63;
    const int lm = ln & 15;
    const int lk = ln >> 4;
    const int base = blockIdx.x * 256 + wv * 64;

    short8v a1[4];
    #pragma unroll
    for (int mt = 0; mt < 4; ++mt) {
        int pt = base + mt * 16 + lm;
        pt = pt < n ? pt : (n - 1);
        union { uint u[4]; short8v v; } c;
        #pragma unroll
        for (int j = 0; j < 4; ++j)
            c.u[j] = feat[(size_t)(lk * 4 + j) * (size_t)n + pt];
        a1[mt] = c.v;
    }

    float4v acc[4][4];
    #pragma unroll
    for (int nt = 0; nt < 4; ++nt) {
        const float bv = b1[nt * 16 + lm];
        #pragma unroll
        for (int mt = 0; mt < 4; ++mt)
            acc[mt][nt] = (float4v){bv, bv, bv, bv};
    }
    #pragma unroll
    for (int nt = 0; nt < 4; ++nt) {
        const short8v bfr = *(const short8v*)(w1t + (nt * 16 + lm) * 32 + lk * 8);
        #pragma unroll
        for (int mt = 0; mt < 4; ++mt)
            acc[mt][nt] = __builtin_amdgcn_mfma_f32_16x16x32_bf16(
                a1[mt], bfr, acc[mt][nt], 0, 0, 0);
    }
    #pragma unroll
    for (int mt = 0; mt < 4; ++mt)
        #pragma unroll
        for (int nt = 0; nt < 4; ++nt)
            #pragma unroll
            for (int r = 0; r < 4; ++r)
                s_h[wv][mt * 16 + lk * 4 + r][nt * 16 + lm] =
                    f2bf(fmaxf(acc[mt][nt][r], 0.f));
    __syncthreads();

    float4v acc2[4][4];
    #pragma unroll
    for (int nt = 0; nt < 4; ++nt) {
        const float bv = b2[nt * 16 + lm];
        #pragma unroll
        for (int mt = 0; mt < 4; ++mt)
            acc2[mt][nt] = (float4v){bv, bv, bv, bv};
    }
    #pragma unroll
    for (int ks = 0; ks < 2; ++ks) {
        short8v a2[4];
        #pragma unroll
        for (int mt = 0; mt < 4; ++mt)
            a2[mt] = *(const short8v*)&s_h[wv][mt * 16 + lm][ks * 32 + lk * 8];
        #pragma unroll
        for (int nt = 0; nt < 4; ++nt) {
            const short8v bfr =
                *(const short8v*)(w2t + (nt * 16 + lm) * 64 + ks * 32 + lk * 8);
            #pragma unroll
            for (int mt = 0; mt < 4; ++mt)
                acc2[mt][nt] = __builtin_amdgcn_mfma_f32_16x16x32_bf16(
                    a2[mt], bfr, acc2[mt][nt], 0, 0, 0);
        }
    }
    __syncthreads();
    #pragma unroll
    for (int mt = 0; mt < 4; ++mt)
        #pragma unroll
        for (int nt = 0; nt < 4; ++nt)
            #pragma unroll
            for (int r = 0; r < 4; ++r)
                s_h[wv][mt * 16 + lk * 4 + r][nt * 16 + lm] =
                    f2bf(fmaxf(acc2[mt][nt][r], 0.f));
    __syncthreads();

    float4v acc3[4];
    const float bv3 = (lm < 3) ? b3[lm] : 0.f;
    #pragma unroll
    for (int mt = 0; mt < 4; ++mt)
        acc3[mt] = (float4v){bv3, bv3, bv3, bv3};
    #pragma unroll
    for (int ks = 0; ks < 2; ++ks) {
        const short8v bfr = *(const short8v*)(w3t + lm * 64 + ks * 32 + lk * 8);
        #pragma unroll
        for (int mt = 0; mt < 4; ++mt) {
            const short8v a3 =
                *(const short8v*)&s_h[wv][mt * 16 + lm][ks * 32 + lk * 8];
            acc3[mt] = __builtin_amdgcn_mfma_f32_16x16x32_bf16(
                a3, bfr, acc3[mt], 0, 0, 0);
        }
    }
    if (lm < 3) {
        #pragma unroll
        for (int mt = 0; mt < 4; ++mt)
            #pragma unroll
            for (int r = 0; r < 4; ++r) {
                const int pt = base + mt * 16 + lk * 4 + r;
                if (pt < n) {
                    const uint o = perm ? perm[pt] : (uint)pt;
                    out[o * 3u + lm] = 1.f / (1.f + __expf(-acc3[mt][r]));
                }
            }
    }
}

// ---------------- last fallback: f32 MLP + h2 encode ----------------
__global__ __launch_bounds__(256)
void ingp_mlp(const __half2* __restrict__ feat16,
              const float* __restrict__ w1, const float* __restrict__ b1,
              const float* __restrict__ w2, const float* __restrict__ b2,
              const float* __restrict__ w3, const float* __restrict__ b3,
              float* __restrict__ out, int n)
{
    __shared__ float s_w1[32 * 64];
    __shared__ float s_w2[64 * 64];
    __shared__ float s_w3[64 * 3];
    __shared__ float s_b1[64];
    __shared__ float s_b2[64];
    __shared__ float s_b3[3];
    for (int t = threadIdx.x; t < 32 * 64; t += 256) s_w1[t] = w1[t];
    for (int t = threadIdx.x; t < 64 * 64; t += 256) s_w2[t] = w2[t];
    for (int t = threadIdx.x; t < 64 * 3;  t += 256) s_w3[t] = w3[t];
    if (threadIdx.x < 64) { s_b1[threadIdx.x] = b1[threadIdx.x]; s_b2[threadIdx.x] = b2[threadIdx.x]; }
    if (threadIdx.x < 3) s_b3[threadIdx.x] = b3[threadIdx.x];
    __syncthreads();
    const int i = blockIdx.x * 256 + threadIdx.x;
    if (i >= n) return;
    float feat[32];
    #pragma unroll
    for (int l = 0; l < LVLS; ++l) {
        const float2 f = __half22float2(feat16[(size_t)l * n + i]);
        feat[2 * l + 0] = f.x;
        feat[2 * l + 1] = f.y;
    }
    float h1[64];
    #pragma unroll
    for (int j = 0; j < 64; ++j) h1[j] = s_b1[j];
    #pragma unroll
    for (int k = 0; k < 32; ++k) {
        const float fv = feat[k];
        #pragma unroll
        for (int j = 0; j < 64; ++j) h1[j] = fmaf(fv, s_w1[k * 64 + j], h1[j]);
    }
    #pragma unroll
    for (int j = 0; j < 64; ++j) h1[j] = fmaxf(h1[j], 0.f);
    float h2[64];
    #pragma unroll
    for (int j = 0; j < 64; ++j) h2[j] = s_b2[j];
    #pragma unroll
    for (int k = 0; k < 64; ++k) {
        const float hv = h1[k];
        #pragma unroll
        for (int j = 0; j < 64; ++j) h2[j] = fmaf(hv, s_w2[k * 64 + j], h2[j]);
    }
    #pragma unroll
    for (int j = 0; j < 64; ++j) h2[j] = fmaxf(h2[j], 0.f);
    float o0 = s_b3[0], o1 = s_b3[1], o2 = s_b3[2];
    #pragma unroll
    for (int j = 0; j < 64; ++j) {
        const float hv = h2[j];
        o0 = fmaf(hv, s_w3[j * 3 + 0], o0);
        o1 = fmaf(hv, s_w3[j * 3 + 1], o1);
        o2 = fmaf(hv, s_w3[j * 3 + 2], o2);
    }
    out[3 * i + 0] = 1.f / (1.f + __expf(-o0));
    out[3 * i + 1] = 1.f / (1.f + __expf(-o1));
    out[3 * i + 2] = 1.f / (1.f + __expf(-o2));
}

__global__ __launch_bounds__(256, 8)
void ingp_encode_h2(const float* __restrict__ x,
                    const float* __restrict__ table,
                    __half2* __restrict__ feat16, int n, ResArr res)
{
    const int i = blockIdx.x * 256 + threadIdx.x;
    const int l = blockIdx.y;
    if (i >= n) return;
    const float xx = x[3 * i + 0], xy = x[3 * i + 1], xz = x[3 * i + 2];
    const float rm1 = res.v[l];
    const float px = xx * rm1, py = xy * rm1, pz = xz * rm1;
    const float fpx = floorf(px), fpy = floorf(py), fpz = floorf(pz);
    const float fx = px - fpx, fy = py - fpy, fz = pz - fpz;
    const uint32_t ix = (uint32_t)fpx, iy = (uint32_t)fpy, iz = (uint32_t)fpz;
    const uint32_t hy0 = iy * PRIME1, hy1 = (iy + 1u) * PRIME1;
    const uint32_t hz0 = iz * PRIME2, hz1 = (iz + 1u) * PRIME2;
    const float* tl = table + (size_t)l * (size_t)TSIZE * 2u;
    float a0 = 0.f, a1 = 0.f;
    #pragma unroll
    for (int c = 0; c < 8; ++c) {
        const int bi = (c >> 2) & 1, bj = (c >> 1) & 1, bk = c & 1;
        const uint32_t h = ((ix + (uint32_t)bi) ^ (bj ? hy1 : hy0) ^ (bk ? hz1 : hz0)) & TMASK;
        const float2 tv = *reinterpret_cast<const float2*>(tl + (size_t)h * 2u);
        const float w = (bi ? fx : 1.f - fx) * (bj ? fy : 1.f - fy) * (bk ? fz : 1.f - fz);
        a0 = fmaf(w, tv.x, a0);
        a1 = fmaf(w, tv.y, a1);
    }
    feat16[(size_t)l * n + i] = __floats2half2_rn(a0, a1);
}

extern "C" void kernel_launch(void* const* d_in, const int* in_sizes, int n_in,
                              void* d_out, int out_size, void* d_ws, size_t ws_size,
                              hipStream_t stream)
{
    const float* x     = (const float*)d_in[0];
    const float* table = (const float*)d_in[1];
    const float* w1    = (const float*)d_in[2];
    const float* b1    = (const float*)d_in[3];
    const float* w2    = (const float*)d_in[4];
    const float* b2    = (const float*)d_in[5];
    const float* w3    = (const float*)d_in[6];
    const float* b3    = (const float*)d_in[7];
    float* out = (float*)d_out;

    const int n = in_sizes[0] / 3;

    ResArr res;
    DenseDims dd;
    {
        const double S = (double)1.3819061f;
        double p = 1.0;
        uint acc = 0;
        for (int l = 0; l < LVLS; ++l) {
            const uint R = (uint)floor(16.0 * p);
            res.v[l] = (float)R - 1.0f;
            if (l < NDENSE) {
                dd.R[l] = R;
                dd.off[l] = acc;
                acc += R * R * R;
            }
            p *= S;
        }
        dd.total = acc;   // 2,190,575 for the default config
    }

    const int gb = (n + 255) / 256;
    const size_t tab16_bytes = (size_t)(LVLS - NDENSE) * TSIZE * 4u;  // 18.9 MB
    const size_t feat_bytes  = (size_t)LVLS * (size_t)n * 4u;         // 32 MB
    const size_t x4_bytes    = (size_t)n * 16u;
    const size_t perm_bytes  = (size_t)n * 4u;
    const size_t dense_bytes = (size_t)dd.total * 4u;                 // 8.8 MB
    const size_t hist_bytes  = (size_t)BINS * 4u;

    const size_t off_tab16 = 16384;
    const size_t off_feat  = off_tab16 + tab16_bytes;
    const size_t off_x4    = off_feat + feat_bytes;
    const size_t off_perm  = off_x4 + x4_bytes;
    const size_t off_dense = off_perm + perm_bytes;
    const size_t off_hist  = off_dense + dense_bytes;
    const size_t off_offs  = off_hist + hist_bytes;
    const size_t off_bsum  = off_offs + hist_bytes;
    const size_t need_new  = off_bsum + 512;
    const size_t need_mid  = 16384 + feat_bytes;

    if (ws_size >= need_new) {
        ushort* w1t   = (ushort*)d_ws;
        ushort* w2t   = w1t + 2048;
        ushort* w3t   = w2t + 4096;
        uint*   tab16 = (uint*)((char*)d_ws + off_tab16);
        uint*   feat  = (uint*)((char*)d_ws + off_feat);
        float4* x4s   = (float4*)((char*)d_ws + off_x4);
        uint*   perm  = (uint*)((char*)d_ws + off_perm);
        uint*   dense = (uint*)((char*)d_ws + off_dense);
        uint*   hist  = (uint*)((char*)d_ws + off_hist);
        uint*   offs  = (uint*)((char*)d_ws + off_offs);
        uint*   bsum  = (uint*)((char*)d_ws + off_bsum);

        hipMemsetAsync(hist, 0, hist_bytes, stream);
        sort_hist<<<gb, 256, 0, stream>>>(x, hist, n);
        scan1<<<BINS / 256, 256, 0, stream>>>(hist, bsum);
        scan2<<<1, 128, 0, stream>>>(bsum);
        scan3<<<BINS / 256, 256, 0, stream>>>(hist, bsum, offs);
        sort_scatter<<<gb, 256, 0, stream>>>(x, offs, x4s, perm, n);

        const int conv_threads = (LVLS - NDENSE) * (int)TSIZE / 2;
        ingp_conv9<<<(conv_threads + 255) / 256, 256, 0, stream>>>(table, tab16);
        dense_build<<<((int)dd.total + 255) / 256, 256, 0, stream>>>(
            table, dense, dd);
        ingp_prep<<<28, 256, 0, stream>>>(w1, w2, w3, w1t, w2t, w3t);

        dim3 gridA(gb, LVLS);
        ingp_encode_ds<<<gridA, 256, 0, stream>>>(x4s, tab16, dense, feat,
                                                  n, res, dd);
        ingp_mlp_mfma<<<gb, 256, 0, stream>>>(feat, w1t, w2t, w3t,
                                              b1, b2, b3, perm, out, n);
    } else if (ws_size >= need_mid) {
        ushort* w1t = (ushort*)d_ws;
        ushort* w2t = w1t + 2048;
        ushort* w3t = w2t + 4096;
        uint*   feat = (uint*)((char*)d_ws + 16384);
        ingp_prep<<<28, 256, 0, stream>>>(w1, w2, w3, w1t, w2t, w3t);
        dim3 gridA(gb, LVLS);
        ingp_encode<<<gridA, 256, 0, stream>>>(x, table, feat, n, res);
        ingp_mlp_mfma<<<gb, 256, 0, stream>>>(feat, w1t, w2t, w3t,
                                              b1, b2, b3, (const uint*)nullptr,
                                              out, n);
    } else {
        dim3 gridA(gb, LVLS);
        ingp_encode_h2<<<gridA, 256, 0, stream>>>(x, table, (__half2*)d_ws, n, res);
        ingp_mlp<<<gb, 256, 0, stream>>>((const __half2*)d_ws,
                                         w1, b1, w2, b2, w3, b3, out, n);
    }
}

// Round 8
// 178.567 us; speedup vs baseline: 1.3362x; 1.3162x over previous
//
#include <hip/hip_runtime.h>
#include <hip/hip_fp16.h>
#include <math.h>

// Instant-NGP forward (round 8):
//   pre:    ONE kernel: table f32 -> fp8-e4m3 (x8192) 2B/entry; x -> float4;
//           weights -> bf16 B^T tables.
//   encode: one thread per (point, level), level-major grid. fp8 tables make
//           the active level slab ~1MB -> L2-resident on every XCD. dim0 hash
//           prime == 1 => corner pair inside one aligned 16B block (8 entries)
//           for 87.5% of ix. Decode = v_cvt_pk_f32_fp8; 2^-13 folded into
//           trilinear weights.
//   mlp:    MFMA bf16 16x16x32; 4 waves/block, 64 points/wave.

constexpr int      LVLS   = 16;
constexpr uint32_t TSIZE  = 1u << 19;
constexpr uint32_t TMASK  = TSIZE - 1u;
constexpr uint32_t PRIME1 = 2654435761u;
constexpr uint32_t PRIME2 = 805459861u;
constexpr float    SCALE_UP = 8192.f;
constexpr float    SCALE_DN = 1.f / 8192.f;

struct ResArr { float v[LVLS]; };  // res[l] - 1.0f

typedef __attribute__((ext_vector_type(8))) short short8v;  // 8 bf16
typedef __attribute__((ext_vector_type(4))) float float4v;  // MFMA acc
typedef __attribute__((ext_vector_type(2))) float float2v;

__device__ inline ushort f2bf(float f) {          // RNE f32 -> bf16
    uint u = __float_as_uint(f);
    u += 0x7fffu + ((u >> 16) & 1u);
    return (ushort)(u >> 16);
}

__device__ inline uint pick4(const uint4& b, uint j) {
    const uint lo = (j & 1u) ? b.y : b.x;
    const uint hi = (j & 1u) ? b.w : b.z;
    return (j & 2u) ? hi : lo;
}

// ---------------- pre: fp8 table + x pack + weight prep (one kernel) -------
__global__ __launch_bounds__(256)
void ingp_pre(const float* __restrict__ table, uint* __restrict__ tab8,
              const float* __restrict__ x, float4* __restrict__ x4,
              const float* __restrict__ w1, const float* __restrict__ w2,
              const float* __restrict__ w3,
              ushort* __restrict__ w1t, ushort* __restrict__ w2t,
              ushort* __restrict__ w3t,
              int n, int bt_tab, int bt_x)
{
    const int b = blockIdx.x;
    if (b < bt_tab) {
        // 2 entries (4 floats) per thread -> one packed uint (4 fp8)
        const int t = b * 256 + threadIdx.x;
        const float4 v = *reinterpret_cast<const float4*>(table + (size_t)t * 4u);
        const int lo = __builtin_amdgcn_cvt_pk_fp8_f32(v.x * SCALE_UP,
                                                       v.y * SCALE_UP, 0, false);
        const int hi = __builtin_amdgcn_cvt_pk_fp8_f32(v.z * SCALE_UP,
                                                       v.w * SCALE_UP, 0, false);
        tab8[t] = ((uint)lo & 0xffffu) | ((uint)hi << 16);
    } else if (b < bt_tab + bt_x) {
        const int i = (b - bt_tab) * 256 + threadIdx.x;
        if (i < n)
            x4[i] = make_float4(x[3 * i + 0], x[3 * i + 1], x[3 * i + 2], 0.f);
    } else {
        const int t = (b - bt_tab - bt_x) * 256 + threadIdx.x;
        if (t < 2048) {                       // w1t[n*32+k] = w1[k*64+n]
            const int nn = t >> 5, k = t & 31;
            w1t[t] = f2bf(w1[k * 64 + nn]);
        } else if (t < 2048 + 4096) {         // w2t[n*64+k] = w2[k*64+n]
            const int q = t - 2048;
            const int nn = q >> 6, k = q & 63;
            w2t[q] = f2bf(w2[k * 64 + nn]);
        } else if (t < 2048 + 4096 + 1024) {  // w3t padded to [16][64]
            const int q = t - 6144;
            const int nn = q >> 6, k = q & 63;
            w3t[q] = (nn < 3) ? f2bf(w3[k * 3 + nn]) : (ushort)0;
        }
    }
}

// ---------------- encode: fp8 table, 8-entry block pair loads --------------
__global__ __launch_bounds__(256, 8)
void ingp_encode_f8(const float4* __restrict__ x4,
                    const ushort* __restrict__ tab8,
                    uint* __restrict__ feat, int n, ResArr res)
{
    const int i = blockIdx.x * 256 + threadIdx.x;
    const int l = blockIdx.y;
    if (i >= n) return;

    const float4 xp = x4[i];
    const float rm1 = res.v[l];
    const float px = xp.x * rm1, py = xp.y * rm1, pz = xp.z * rm1;
    const float fpx = floorf(px), fpy = floorf(py), fpz = floorf(pz);
    const float fx = px - fpx, fy = py - fpy, fz = pz - fpz;
    const uint32_t ix = (uint32_t)fpx;
    const uint32_t iy = (uint32_t)fpy;
    const uint32_t iz = (uint32_t)fpz;
    const uint32_t hy0 = iy * PRIME1, hy1 = (iy + 1u) * PRIME1;
    const uint32_t hz0 = iz * PRIME2, hz1 = (iz + 1u) * PRIME2;
    const ushort* tl = tab8 + (size_t)l * (size_t)TSIZE;

    uint32_t h0[4], h1[4];
    #pragma unroll
    for (int p = 0; p < 4; ++p) {
        const uint32_t bj = (p >> 1) & 1, bk = p & 1;
        const uint32_t hyz = (bj ? hy1 : hy0) ^ (bk ? hz1 : hz0);
        h0[p] = (ix ^ hyz) & TMASK;
        h1[p] = ((ix + 1u) ^ hyz) & TMASK;
    }

    // pair distance d = ix^(ix+1) <= 7 for 87.5% of ix -> both corners in one
    // aligned 8-entry (16B) block. Masked scalar fixup otherwise.
    const bool fast = (ix & 7u) != 7u;
    float2v c0v[4], c1v[4];
    #pragma unroll
    for (int p = 0; p < 4; ++p) {
        const uint32_t base = h0[p] & ~7u;
        const uint4 blk = *reinterpret_cast<const uint4*>(tl + base);
        const uint j0 = h0[p] & 7u;
        const uint w0 = pick4(blk, j0 >> 1) >> ((j0 & 1u) << 4);
        c0v[p] = __builtin_amdgcn_cvt_pk_f32_fp8((int)w0, false);
        const uint j1 = h1[p] & 7u;
        const uint w1e = pick4(blk, j1 >> 1) >> ((j1 & 1u) << 4);
        c1v[p] = __builtin_amdgcn_cvt_pk_f32_fp8((int)w1e, false);
    }
    if (!fast) {
        #pragma unroll
        for (int p = 0; p < 4; ++p)
            c1v[p] = __builtin_amdgcn_cvt_pk_f32_fp8((int)tl[h1[p]], false);
    }

    const float gx0 = (1.f - fx) * SCALE_DN, gx1 = fx * SCALE_DN;
    float a0 = 0.f, a1 = 0.f;
    #pragma unroll
    for (int p = 0; p < 4; ++p) {
        const int bj = (p >> 1) & 1, bk = p & 1;
        const float wyz = (bj ? fy : 1.f - fy) * (bk ? fz : 1.f - fz);
        const float w0 = wyz * gx0, w1 = wyz * gx1;
        a0 = fmaf(w0, c0v[p].x, a0);
        a1 = fmaf(w0, c0v[p].y, a1);
        a0 = fmaf(w1, c1v[p].x, a0);
        a1 = fmaf(w1, c1v[p].y, a1);
    }
    feat[(size_t)l * n + i] = (uint)f2bf(a0) | ((uint)f2bf(a1) << 16);
}

// ---------------- Kernel B: MFMA MLP ----------------
__global__ __launch_bounds__(256)
void ingp_mlp_mfma(const uint* __restrict__ feat,
                   const ushort* __restrict__ w1t,
                   const ushort* __restrict__ w2t,
                   const ushort* __restrict__ w3t,
                   const float* __restrict__ b1,
                   const float* __restrict__ b2,
                   const float* __restrict__ b3,
                   float* __restrict__ out, int n)
{
    __shared__ ushort s_h[4][64][72];
    const int tid = threadIdx.x;
    const int wv = tid >> 6;
    const int ln = tid & 63;
    const int lm = ln & 15;
    const int lk = ln >> 4;
    const int base = blockIdx.x * 256 + wv * 64;

    short8v a1[4];
    #pragma unroll
    for (int mt = 0; mt < 4; ++mt) {
        int pt = base + mt * 16 + lm;
        pt = pt < n ? pt : (n - 1);
        union { uint u[4]; short8v v; } c;
        #pragma unroll
        for (int j = 0; j < 4; ++j)
            c.u[j] = feat[(size_t)(lk * 4 + j) * (size_t)n + pt];
        a1[mt] = c.v;
    }

    float4v acc[4][4];
    #pragma unroll
    for (int nt = 0; nt < 4; ++nt) {
        const float bv = b1[nt * 16 + lm];
        #pragma unroll
        for (int mt = 0; mt < 4; ++mt)
            acc[mt][nt] = (float4v){bv, bv, bv, bv};
    }
    #pragma unroll
    for (int nt = 0; nt < 4; ++nt) {
        const short8v bfr = *(const short8v*)(w1t + (nt * 16 + lm) * 32 + lk * 8);
        #pragma unroll
        for (int mt = 0; mt < 4; ++mt)
            acc[mt][nt] = __builtin_amdgcn_mfma_f32_16x16x32_bf16(
                a1[mt], bfr, acc[mt][nt], 0, 0, 0);
    }
    #pragma unroll
    for (int mt = 0; mt < 4; ++mt)
        #pragma unroll
        for (int nt = 0; nt < 4; ++nt)
            #pragma unroll
            for (int r = 0; r < 4; ++r)
                s_h[wv][mt * 16 + lk * 4 + r][nt * 16 + lm] =
                    f2bf(fmaxf(acc[mt][nt][r], 0.f));
    __syncthreads();

    float4v acc2[4][4];
    #pragma unroll
    for (int nt = 0; nt < 4; ++nt) {
        const float bv = b2[nt * 16 + lm];
        #pragma unroll
        for (int mt = 0; mt < 4; ++mt)
            acc2[mt][nt] = (float4v){bv, bv, bv, bv};
    }
    #pragma unroll
    for (int ks = 0; ks < 2; ++ks) {
        short8v a2[4];
        #pragma unroll
        for (int mt = 0; mt < 4; ++mt)
            a2[mt] = *(const short8v*)&s_h[wv][mt * 16 + lm][ks * 32 + lk * 8];
        #pragma unroll
        for (int nt = 0; nt < 4; ++nt) {
            const short8v bfr =
                *(const short8v*)(w2t + (nt * 16 + lm) * 64 + ks * 32 + lk * 8);
            #pragma unroll
            for (int mt = 0; mt < 4; ++mt)
                acc2[mt][nt] = __builtin_amdgcn_mfma_f32_16x16x32_bf16(
                    a2[mt], bfr, acc2[mt][nt], 0, 0, 0);
        }
    }
    __syncthreads();
    #pragma unroll
    for (int mt = 0; mt < 4; ++mt)
        #pragma unroll
        for (int nt = 0; nt < 4; ++nt)
            #pragma unroll
            for (int r = 0; r < 4; ++r)
                s_h[wv][mt * 16 + lk * 4 + r][nt * 16 + lm] =
                    f2bf(fmaxf(acc2[mt][nt][r], 0.f));
    __syncthreads();

    float4v acc3[4];
    const float bv3 = (lm < 3) ? b3[lm] : 0.f;
    #pragma unroll
    for (int mt = 0; mt < 4; ++mt)
        acc3[mt] = (float4v){bv3, bv3, bv3, bv3};
    #pragma unroll
    for (int ks = 0; ks < 2; ++ks) {
        const short8v bfr = *(const short8v*)(w3t + lm * 64 + ks * 32 + lk * 8);
        #pragma unroll
        for (int mt = 0; mt < 4; ++mt) {
            const short8v a3 =
                *(const short8v*)&s_h[wv][mt * 16 + lm][ks * 32 + lk * 8];
            acc3[mt] = __builtin_amdgcn_mfma_f32_16x16x32_bf16(
                a3, bfr, acc3[mt], 0, 0, 0);
        }
    }
    if (lm < 3) {
        #pragma unroll
        for (int mt = 0; mt < 4; ++mt)
            #pragma unroll
            for (int r = 0; r < 4; ++r) {
                const int pt = base + mt * 16 + lk * 4 + r;
                if (pt < n)
                    out[pt * 3 + lm] = 1.f / (1.f + __expf(-acc3[mt][r]));
            }
    }
}

// ---------------- mid fallback: f32 table, paired-corner loads ------------
__global__ __launch_bounds__(256, 8)
void ingp_encode(const float* __restrict__ x,
                 const float* __restrict__ table,
                 uint* __restrict__ feat, int n, ResArr res)
{
    const int i = blockIdx.x * 256 + threadIdx.x;
    const int l = blockIdx.y;
    if (i >= n) return;
    const float xx = x[3 * i + 0], xy = x[3 * i + 1], xz = x[3 * i + 2];
    const float rm1 = res.v[l];
    const float px = xx * rm1, py = xy * rm1, pz = xz * rm1;
    const float fpx = floorf(px), fpy = floorf(py), fpz = floorf(pz);
    const float fx = px - fpx, fy = py - fpy, fz = pz - fpz;
    const uint32_t ix = (uint32_t)fpx, iy = (uint32_t)fpy, iz = (uint32_t)fpz;
    const uint32_t hy0 = iy * PRIME1, hy1 = (iy + 1u) * PRIME1;
    const uint32_t hz0 = iz * PRIME2, hz1 = (iz + 1u) * PRIME2;
    const float* tl = table + (size_t)l * (size_t)TSIZE * 2u;

    uint32_t idx0[4], idx1[4];
    #pragma unroll
    for (int p = 0; p < 4; ++p) {
        const uint32_t bj = (p >> 1) & 1, bk = p & 1;
        const uint32_t hyz = (bj ? hy1 : hy0) ^ (bk ? hz1 : hz0);
        idx0[p] = (ix ^ hyz) & TMASK;
        idx1[p] = ((ix + 1u) ^ hyz) & TMASK;
    }
    float2 c0[4], c1[4];
    if ((ix & 1u) == 0u) {
        #pragma unroll
        for (int p = 0; p < 4; ++p) {
            const uint32_t base = idx0[p] & ~1u;
            const float4 q = *reinterpret_cast<const float4*>(tl + (size_t)base * 2u);
            if (idx0[p] & 1u) { c0[p] = make_float2(q.z, q.w); c1[p] = make_float2(q.x, q.y); }
            else              { c0[p] = make_float2(q.x, q.y); c1[p] = make_float2(q.z, q.w); }
        }
    } else {
        #pragma unroll
        for (int p = 0; p < 4; ++p) {
            c0[p] = *reinterpret_cast<const float2*>(tl + (size_t)idx0[p] * 2u);
            c1[p] = *reinterpret_cast<const float2*>(tl + (size_t)idx1[p] * 2u);
        }
    }
    const float gx0 = 1.f - fx, gx1 = fx;
    float a0 = 0.f, a1 = 0.f;
    #pragma unroll
    for (int p = 0; p < 4; ++p) {
        const int bj = (p >> 1) & 1, bk = p & 1;
        const float wyz = (bj ? fy : 1.f - fy) * (bk ? fz : 1.f - fz);
        const float w0 = wyz * gx0, w1 = wyz * gx1;
        a0 = fmaf(w0, c0[p].x, a0);
        a1 = fmaf(w0, c0[p].y, a1);
        a0 = fmaf(w1, c1[p].x, a0);
        a1 = fmaf(w1, c1[p].y, a1);
    }
    feat[(size_t)l * n + i] = (uint)f2bf(a0) | ((uint)f2bf(a1) << 16);
}

__global__ __launch_bounds__(256)
void ingp_prep(const float* __restrict__ w1, const float* __restrict__ w2,
               const float* __restrict__ w3,
               ushort* __restrict__ w1t, ushort* __restrict__ w2t,
               ushort* __restrict__ w3t)
{
    const int t = blockIdx.x * 256 + threadIdx.x;
    if (t < 2048) {
        const int nn = t >> 5, k = t & 31;
        w1t[t] = f2bf(w1[k * 64 + nn]);
    } else if (t < 2048 + 4096) {
        const int q = t - 2048;
        const int nn = q >> 6, k = q & 63;
        w2t[q] = f2bf(w2[k * 64 + nn]);
    } else if (t < 2048 + 4096 + 1024) {
        const int q = t - 6144;
        const int nn = q >> 6, k = q & 63;
        w3t[q] = (nn < 3) ? f2bf(w3[k * 3 + nn]) : (ushort)0;
    }
}

extern "C" void kernel_launch(void* const* d_in, const int* in_sizes, int n_in,
                              void* d_out, int out_size, void* d_ws, size_t ws_size,
                              hipStream_t stream)
{
    const float* x     = (const float*)d_in[0];
    const float* table = (const float*)d_in[1];
    const float* w1    = (const float*)d_in[2];
    const float* b1    = (const float*)d_in[3];
    const float* w2    = (const float*)d_in[4];
    const float* b2    = (const float*)d_in[5];
    const float* w3    = (const float*)d_in[6];
    const float* b3    = (const float*)d_in[7];
    float* out = (float*)d_out;

    const int n = in_sizes[0] / 3;

    ResArr res;
    {
        const double S = (double)1.3819061f;
        double p = 1.0;
        for (int l = 0; l < LVLS; ++l) {
            res.v[l] = (float)floor(16.0 * p) - 1.0f;
            p *= S;
        }
    }

    const int gb = (n + 255) / 256;
    const size_t tab8_bytes = (size_t)LVLS * TSIZE * 2u;          // 16.8 MB
    const size_t feat_bytes = (size_t)LVLS * (size_t)n * 4u;      // 32 MB
    const size_t x4_bytes   = (size_t)n * 16u;                    // 8 MB

    const size_t off_tab8 = 32768;
    const size_t off_feat = off_tab8 + tab8_bytes;
    const size_t off_x4   = off_feat + feat_bytes;
    const size_t need_f8  = off_x4 + x4_bytes;                    // ~57 MB
    const size_t need_mid = 16384 + feat_bytes;

    if (ws_size >= need_f8) {
        ushort* w1t  = (ushort*)d_ws;
        ushort* w2t  = w1t + 2048;
        ushort* w3t  = w2t + 4096;
        uint*   tab8 = (uint*)((char*)d_ws + off_tab8);
        uint*   feat = (uint*)((char*)d_ws + off_feat);
        float4* x4   = (float4*)((char*)d_ws + off_x4);

        const int bt_tab = (LVLS * (int)TSIZE / 2) / 256;   // 16384 blocks
        const int bt_x   = gb;                              // 1954
        const int bt_w   = 28;
        ingp_pre<<<bt_tab + bt_x + bt_w, 256, 0, stream>>>(
            table, tab8, x, x4, w1, w2, w3, w1t, w2t, w3t, n, bt_tab, bt_x);

        dim3 gridA(gb, LVLS);
        ingp_encode_f8<<<gridA, 256, 0, stream>>>(x4, (const ushort*)tab8,
                                                  feat, n, res);
        ingp_mlp_mfma<<<gb, 256, 0, stream>>>(feat, w1t, w2t, w3t,
                                              b1, b2, b3, out, n);
    } else if (ws_size >= need_mid) {
        ushort* w1t = (ushort*)d_ws;
        ushort* w2t = w1t + 2048;
        ushort* w3t = w2t + 4096;
        uint*   feat = (uint*)((char*)d_ws + 16384);
        ingp_prep<<<28, 256, 0, stream>>>(w1, w2, w3, w1t, w2t, w3t);
        dim3 gridA(gb, LVLS);
        ingp_encode<<<gridA, 256, 0, stream>>>(x, table, feat, n, res);
        ingp_mlp_mfma<<<gb, 256, 0, stream>>>(feat, w1t, w2t, w3t,
                                              b1, b2, b3, out, n);
    }
    // (ws_size is always >= need_mid in this harness; no further fallback)
}